// Round 10
// baseline (244.772 us; speedup 1.0000x reference)
//
#include <hip/hip_runtime.h>

#define S_LEN 4096
#define DMODEL 1024
#define NHEADS 16

typedef __attribute__((ext_vector_type(8))) short bf16x8;
typedef __attribute__((ext_vector_type(4))) float f32x4;
typedef unsigned short u16;
typedef unsigned int u32;
typedef unsigned long long u64;

__device__ inline u16 f2bf(float f) {
    union { float f; u32 u; } v; v.f = f;
    u32 r = v.u + 0x7fffu + ((v.u >> 16) & 1u);
    return (u16)(r >> 16);
}

// pack two fp32 -> two bf16 (RNE) in one u32 via v_perm_b32. low16 = a.
__device__ inline u32 pkbf2(float a, float b) {
    union { float f; u32 u; } ua, ub; ua.f = a; ub.f = b;
    const u32 ra = ua.u + 0x7fffu + ((ua.u >> 16) & 1u);
    const u32 rb = ub.u + 0x7fffu + ((ub.u >> 16) & 1u);
    return __builtin_amdgcn_perm(rb, ra, 0x07060302u);
}

// async 16B global->LDS DMA. LDS dst = wave-uniform base + lane*16 at all sites.
__device__ inline void cp16(const void* g, void* l) {
    __builtin_amdgcn_global_load_lds(
        (const __attribute__((address_space(1))) unsigned int*)g,
        (__attribute__((address_space(3))) unsigned int*)l, 16, 0, 0);
}

// One launch converts x (4M), wq/wk/wv (-> w3 contiguous), wo (-> wob). 4096 blocks.
__global__ __launch_bounds__(256) void cvt_all(const float* __restrict__ x,
                                               const float* __restrict__ wq,
                                               const float* __restrict__ wk,
                                               const float* __restrict__ wv,
                                               const float* __restrict__ wo,
                                               u16* __restrict__ xb,
                                               u16* __restrict__ w3,
                                               u16* __restrict__ wob) {
    const int b = blockIdx.x;
    const float* s; u16* d; int off;
    const int NW = DMODEL * DMODEL;  // 1M
    if (b < 2048)      { s = x;  d = xb;          off = b * 2048; }
    else if (b < 2560) { s = wq; d = w3;          off = (b - 2048) * 2048; }
    else if (b < 3072) { s = wk; d = w3 + NW;     off = (b - 2560) * 2048; }
    else if (b < 3584) { s = wv; d = w3 + 2 * NW; off = (b - 3072) * 2048; }
    else               { s = wo; d = wob;         off = (b - 3584) * 2048; }
    const int i = off + threadIdx.x * 8;
    const float4 a = *(const float4*)(s + i);
    const float4 c = *(const float4*)(s + i + 4);
    u16 t[8];
    t[0] = f2bf(a.x); t[1] = f2bf(a.y); t[2] = f2bf(a.z); t[3] = f2bf(a.w);
    t[4] = f2bf(c.x); t[5] = f2bf(c.y); t[6] = f2bf(c.z); t[7] = f2bf(c.w);
    *(bf16x8*)(d + i) = *(const bf16x8*)t;
}

// Fused QKV projection: C = x(4096x1024) * W3^T (W3 = [wq;wk;wv] 3072x1024).
// Double-buffered single-barrier K-loop (BK=32). Q pre-scaled by 1/8*log2e.
// Q,K -> [h][m][c]; V -> [h][c][m].
__global__ __launch_bounds__(256) void gemm_qkv(const u16* __restrict__ A,
                                                const u16* __restrict__ B3,
                                                u16* __restrict__ Qo,
                                                u16* __restrict__ Ko,
                                                u16* __restrict__ Vo) {
    __shared__ __align__(16) u16 As[2][128 * 32];
    __shared__ __align__(16) u16 Bs[2][128 * 32];
    const int tid = threadIdx.x, lane = tid & 63, wave = tid >> 6;
    const int wm = (wave >> 1) * 64, wn = (wave & 1) * 64;
    const int m0 = blockIdx.y * 128, n0 = blockIdx.x * 128;
    const int l15 = lane & 15, quad = lane >> 4;

    f32x4 acc[4][4];
#pragma unroll
    for (int i = 0; i < 4; i++)
#pragma unroll
        for (int j = 0; j < 4; j++) acc[i][j] = (f32x4){0.f, 0.f, 0.f, 0.f};

    const int r0 = tid >> 2, c0 = (tid & 3) * 8;

    // prologue: stage k=0 into buf 0
    cp16(A + (size_t)(m0 + r0) * 1024 + c0,       As[0] + r0 * 32 + c0);
    cp16(A + (size_t)(m0 + r0 + 64) * 1024 + c0,  As[0] + (r0 + 64) * 32 + c0);
    cp16(B3 + (size_t)(n0 + r0) * 1024 + c0,      Bs[0] + r0 * 32 + c0);
    cp16(B3 + (size_t)(n0 + r0 + 64) * 1024 + c0, Bs[0] + (r0 + 64) * 32 + c0);

    int cur = 0;
    for (int kk = 0; kk < 1024; kk += 32) {
        __syncthreads();  // drains vmcnt(0): buf[cur] ready, buf[cur^1] reads done
        if (kk + 32 < 1024) {
            const int kn = kk + 32;
            cp16(A + (size_t)(m0 + r0) * 1024 + kn + c0,       As[cur ^ 1] + r0 * 32 + c0);
            cp16(A + (size_t)(m0 + r0 + 64) * 1024 + kn + c0,  As[cur ^ 1] + (r0 + 64) * 32 + c0);
            cp16(B3 + (size_t)(n0 + r0) * 1024 + kn + c0,      Bs[cur ^ 1] + r0 * 32 + c0);
            cp16(B3 + (size_t)(n0 + r0 + 64) * 1024 + kn + c0, Bs[cur ^ 1] + (r0 + 64) * 32 + c0);
        }
        bf16x8 af[4], bfr[4];
#pragma unroll
        for (int i = 0; i < 4; i++)
            af[i] = *(const bf16x8*)(As[cur] + (wm + i * 16 + l15) * 32 + quad * 8);
#pragma unroll
        for (int j = 0; j < 4; j++)
            bfr[j] = *(const bf16x8*)(Bs[cur] + (wn + j * 16 + l15) * 32 + quad * 8);
#pragma unroll
        for (int i = 0; i < 4; i++)
#pragma unroll
            for (int j = 0; j < 4; j++)
                acc[i][j] = __builtin_amdgcn_mfma_f32_16x16x32_bf16(af[i], bfr[j], acc[i][j], 0, 0, 0);
        cur ^= 1;
    }

    const int which = n0 >> 10;
    const int n0r = n0 & 1023;
    u16* dst = (which == 0) ? Qo : (which == 1) ? Ko : Vo;
    const float sc = (which == 0) ? 0.125f * 1.4426950408889634f : 1.0f;
#pragma unroll
    for (int i = 0; i < 4; i++)
#pragma unroll
        for (int j = 0; j < 4; j++)
#pragma unroll
            for (int r = 0; r < 4; r++) {
                const int row = m0 + wm + i * 16 + quad * 4 + r;
                const int col = n0r + wn + j * 16 + l15;
                const int h = col >> 6, c = col & 63;
                const u16 v = f2bf(acc[i][j][r] * sc);
                if (which < 2) dst[(size_t)h * S_LEN * 64 + (size_t)row * 64 + c] = v;
                else           dst[(size_t)h * S_LEN * 64 + (size_t)c * S_LEN + row] = v;
            }
}

// Output projection: C(fp32 [4096][1024]) = y(bf16) * wo^T. Split-M:
// 64x128 tiles, grid 512 (2/CU), BK=64, dbuf single-barrier, swizzled LDS,
// plain coalesced fp32 stores (no atomics, no memset).
__global__ __launch_bounds__(256) void gemm_out(const u16* __restrict__ A,
                                                const u16* __restrict__ B,
                                                float* __restrict__ C) {
    __shared__ __align__(16) u16 As[2][64 * 64];    // swizzled [row][col]
    __shared__ __align__(16) u16 Bs[2][128 * 64];   // swizzled [row][col]
    const int tid = threadIdx.x, lane = tid & 63, wave = tid >> 6;
    const int wm = (wave >> 1) * 32, wn = (wave & 1) * 64;
    const int bx = blockIdx.x;
    const int n0 = (bx & 7) * 128, m0 = (bx >> 3) * 64;
    const int l15 = lane & 15, quad = lane >> 4;
    const int swz = l15 & 7;

    f32x4 acc[2][4];
#pragma unroll
    for (int i = 0; i < 2; i++)
#pragma unroll
        for (int j = 0; j < 4; j++) acc[i][j] = (f32x4){0.f, 0.f, 0.f, 0.f};

#define STAGE_OUT(buf, kb)                                                              \
    {                                                                                   \
        _Pragma("unroll")                                                               \
        for (int q = 0; q < 2; q++) {                                                   \
            const int ch = tid + q * 256;                                               \
            const int ar = ch >> 3, ac = ((ch & 7) ^ (ar & 7)) * 8;                     \
            cp16(A + (size_t)(m0 + ar) * 1024 + (kb) + ac, As[buf] + ch * 8);           \
        }                                                                               \
        _Pragma("unroll")                                                               \
        for (int q = 0; q < 4; q++) {                                                   \
            const int ch = tid + q * 256;                                               \
            const int br = ch >> 3, bc = ((ch & 7) ^ (br & 7)) * 8;                     \
            cp16(B + (size_t)(n0 + br) * 1024 + (kb) + bc, Bs[buf] + ch * 8);           \
        }                                                                               \
    }

    STAGE_OUT(0, 0);
    int cur = 0;
    for (int kk = 0; kk < 1024; kk += 64) {
        __syncthreads();  // drains vmcnt(0): buf[cur] ready, buf[cur^1] reads done
        if (kk + 64 < 1024) STAGE_OUT(cur ^ 1, kk + 64);
#pragma unroll
        for (int h = 0; h < 2; h++) {
            const int cc = (h * 4 + quad) ^ swz;
            bf16x8 af[2], bfr[4];
#pragma unroll
            for (int i = 0; i < 2; i++)
                af[i] = *(const bf16x8*)(As[cur] + (wm + i * 16 + l15) * 64 + cc * 8);
#pragma unroll
            for (int j = 0; j < 4; j++)
                bfr[j] = *(const bf16x8*)(Bs[cur] + (wn + j * 16 + l15) * 64 + cc * 8);
#pragma unroll
            for (int i = 0; i < 2; i++)
#pragma unroll
                for (int j = 0; j < 4; j++)
                    acc[i][j] = __builtin_amdgcn_mfma_f32_16x16x32_bf16(af[i], bfr[j], acc[i][j], 0, 0, 0);
        }
        cur ^= 1;
    }
#undef STAGE_OUT

#pragma unroll
    for (int i = 0; i < 2; i++)
#pragma unroll
        for (int j = 0; j < 4; j++)
#pragma unroll
            for (int r = 0; r < 4; r++) {
                const int row = m0 + wm + i * 16 + quad * 4 + r;
                const int col = n0 + wn + j * 16 + l15;
                C[(size_t)row * 1024 + col] = acc[i][j][r];
            }
}

// Flash attention, causal. Block = 4 waves x 16 q-rows = one 64-row q-tile.
// 32-key K-tiles, double-buffered. Grid 1024 = 4 blocks/CU (16 waves/CU).
// Job map: i=b&255, k=b>>8, head=i&15, s=i>>4, j={s,31-s,32+s,63-s}[k]:
// cost 2j+2 sums to 260 over the 4-set AND is head-independent -> balanced
// under stride-256 round-robin or contiguous dispatch.
// Q (pre-scaled), K: [H][S][64] bf16. Vt: [H][64][S] bf16. Y: [S][DMODEL] bf16.
__global__ __launch_bounds__(256) void attn(const u16* __restrict__ Q,
                                            const u16* __restrict__ Kh,
                                            const u16* __restrict__ Vt,
                                            u16* __restrict__ Y) {
    __shared__ __align__(16) u16 Ks[2][32 * 64];   // swizzled [key][dim]
    __shared__ __align__(16) u16 Vs[2][64 * 32];   // swizzled [dim][key]
    __shared__ __align__(16) u16 Pl[4][16 * 36];   // [q][key], stride 36
    const int b = blockIdx.x;
    const int i_ = b & 255, k_ = b >> 8;
    const int head = i_ & 15, s_ = i_ >> 4;
    const int j = (k_ == 0) ? s_ : (k_ == 1) ? 31 - s_ : (k_ == 2) ? 32 + s_ : 63 - s_;
    const int nkt = 2 * j + 2;
    const int tid = threadIdx.x, lane = tid & 63, w = tid >> 6;
    const int l15 = lane & 15, quad = lane >> 4;
    const int swz = l15 & 7;

    const u16* Qp = Q + (size_t)head * S_LEN * 64;
    const u16* Kp = Kh + (size_t)head * S_LEN * 64;
    const u16* Vp = Vt + (size_t)head * 64 * S_LEN;

    const int qbase = 64 * j + w * 16;
    const int qrow = qbase + l15;

    // staging: thread tid owns LDS chunk tid (cp16 dst is lane*16 forced);
    // inverse-swizzle the GLOBAL column so reads are conflict-spread.
    const int krow = tid >> 3;                       // key 0..31
    const int kcol = ((tid & 7) ^ (krow & 7)) * 8;   // dim chunk
    const int vrow = tid >> 2;                       // dim 0..63
    const int vcol = ((tid & 3) ^ (vrow & 3)) * 8;   // key chunk

    bf16x8 aq[2];
#pragma unroll
    for (int s = 0; s < 2; s++)
        aq[s] = *(const bf16x8*)(Qp + (size_t)qrow * 64 + s * 32 + quad * 8);

    f32x4 o[4];
#pragma unroll
    for (int jj = 0; jj < 4; jj++) o[jj] = (f32x4){0.f, 0.f, 0.f, 0.f};
    float lrow = 0.f;

    // prologue: stage tile 0 into buf 0
    cp16(Kp + (size_t)krow * 64 + kcol,   Ks[0] + tid * 8);
    cp16(Vp + (size_t)vrow * S_LEN + vcol, Vs[0] + tid * 8);

    int cur = 0;
    for (int kt = 0; kt < nkt; kt++) {
        __syncthreads();  // drains vmcnt(0): buf[cur] ready, buf[cur^1] reads done
        if (kt + 1 < nkt) {
            const int kn = (kt + 1) * 32;
            cp16(Kp + (size_t)(kn + krow) * 64 + kcol,   Ks[cur ^ 1] + tid * 8);
            cp16(Vp + (size_t)vrow * S_LEN + kn + vcol,  Vs[cur ^ 1] + tid * 8);
        }
        const int kb = kt * 32;
        const bool act = (kb <= qbase + 15);  // wave-uniform: any key visible?
        if (act) {
            const u16* K_ = Ks[cur];
            const u16* V_ = Vs[cur];
            const bool bnd = (kb + 31 > qbase);  // wave-uniform mask needed?
#pragma unroll
            for (int t = 0; t < 2; t++) {
                const bf16x8 k0 = *(const bf16x8*)(K_ + (t * 16 + l15) * 64 + (quad ^ swz) * 8);
                const bf16x8 k1 = *(const bf16x8*)(K_ + (t * 16 + l15) * 64 + ((4 + quad) ^ swz) * 8);
                f32x4 c = (f32x4){0.f, 0.f, 0.f, 0.f};
                c = __builtin_amdgcn_mfma_f32_16x16x32_bf16(k0, aq[0], c, 0, 0, 0);
                c = __builtin_amdgcn_mfma_f32_16x16x32_bf16(k1, aq[1], c, 0, 0, 0);
                const int keyb = kb + t * 16 + quad * 4;
                float p[4];
#pragma unroll
                for (int r = 0; r < 4; r++) {
                    p[r] = __builtin_amdgcn_exp2f(c[r]);
                    if (bnd && (keyb + r > qrow)) p[r] = 0.f;
                }
                lrow += (p[0] + p[1]) + (p[2] + p[3]);
                const u32 w0 = pkbf2(p[0], p[1]);
                const u32 w1 = pkbf2(p[2], p[3]);
                *(u64*)(&Pl[w][l15 * 36 + t * 16 + quad * 4]) = (u64)w0 | ((u64)w1 << 32);
            }
            const bf16x8 pf = *(const bf16x8*)(&Pl[w][l15 * 36 + quad * 8]);
#pragma unroll
            for (int jj = 0; jj < 4; jj++) {
                const bf16x8 v = *(const bf16x8*)(V_ + (jj * 16 + l15) * 32 +
                                                  (quad ^ (l15 & 3)) * 8);
                o[jj] = __builtin_amdgcn_mfma_f32_16x16x32_bf16(v, pf, o[jj], 0, 0, 0);
            }
        }
        cur ^= 1;
    }

    lrow += __shfl_xor(lrow, 16);
    lrow += __shfl_xor(lrow, 32);
    const float inv = 1.f / lrow;
#pragma unroll
    for (int jj = 0; jj < 4; jj++) {
        const u32 w0 = pkbf2(o[jj][0] * inv, o[jj][1] * inv);
        const u32 w1 = pkbf2(o[jj][2] * inv, o[jj][3] * inv);
        *(u64*)(Y + (size_t)qrow * DMODEL + head * 64 + jj * 16 + quad * 4) =
            (u64)w0 | ((u64)w1 << 32);
    }
}

extern "C" void kernel_launch(void* const* d_in, const int* in_sizes, int n_in,
                              void* d_out, int out_size, void* d_ws, size_t ws_size,
                              hipStream_t stream) {
    const float* x  = (const float*)d_in[0];
    const float* wq = (const float*)d_in[1];
    const float* wk = (const float*)d_in[2];
    const float* wv = (const float*)d_in[3];
    const float* wo = (const float*)d_in[4];
    float* out = (float*)d_out;

    u16* qh  = (u16*)d_ws;                            // [0,8) MB
    u16* kh  = qh + (size_t)S_LEN * DMODEL;           // [8,16)
    u16* vt  = kh + (size_t)S_LEN * DMODEL;           // [16,24)
    u16* xb  = vt + (size_t)S_LEN * DMODEL;           // [24,32) x bf16, later y
    u16* y   = xb;                                    // alias after QKV proj
    u16* wb3 = xb + (size_t)S_LEN * DMODEL;           // [32,38) [wq;wk;wv]
    u16* wob = wb3 + (size_t)3 * DMODEL * DMODEL;     // [38,40) wo bf16

    const dim3 blk(256);

    cvt_all<<<4096, blk, 0, stream>>>(x, wq, wk, wv, wo, xb, wb3, wob);
    gemm_qkv<<<dim3(3 * DMODEL / 128, S_LEN / 128), blk, 0, stream>>>(xb, wb3, qh, kh, vt);
    attn<<<1024, blk, 0, stream>>>(qh, kh, vt, y);
    gemm_out<<<512, blk, 0, stream>>>(y, wob, out);
}

// Round 11
// 220.628 us; speedup vs baseline: 1.1094x; 1.1094x over previous
//
#include <hip/hip_runtime.h>

#define S_LEN 4096
#define DMODEL 1024
#define NHEADS 16

typedef __attribute__((ext_vector_type(8))) short bf16x8;
typedef __attribute__((ext_vector_type(4))) float f32x4;
typedef unsigned short u16;
typedef unsigned int u32;
typedef unsigned long long u64;

__device__ inline u16 f2bf(float f) {
    union { float f; u32 u; } v; v.f = f;
    u32 r = v.u + 0x7fffu + ((v.u >> 16) & 1u);
    return (u16)(r >> 16);
}

// exact RNE pack (epilogue use)
__device__ inline u32 pkbf2(float a, float b) {
    union { float f; u32 u; } ua, ub; ua.f = a; ub.f = b;
    const u32 ra = ua.u + 0x7fffu + ((ua.u >> 16) & 1u);
    const u32 rb = ub.u + 0x7fffu + ((ub.u >> 16) & 1u);
    return __builtin_amdgcn_perm(rb, ra, 0x07060302u);
}

// fast pack: round-half-up (3 VALU ops). Differs from RNE only at exact ties.
__device__ inline u32 pkbf2f(float a, float b) {
    union { float f; u32 u; } ua, ub; ua.f = a; ub.f = b;
    const u32 ra = ua.u + 0x8000u;
    const u32 rb = ub.u + 0x8000u;
    return __builtin_amdgcn_perm(rb, ra, 0x07060302u);
}

// async 16B global->LDS DMA. LDS dst = wave-uniform base + lane*16 at all sites.
__device__ inline void cp16(const void* g, void* l) {
    __builtin_amdgcn_global_load_lds(
        (const __attribute__((address_space(1))) unsigned int*)g,
        (__attribute__((address_space(3))) unsigned int*)l, 16, 0, 0);
}

// One launch converts x (4M), wq/wk/wv (-> w3 contiguous), wo (-> wob). 4096 blocks.
__global__ __launch_bounds__(256) void cvt_all(const float* __restrict__ x,
                                               const float* __restrict__ wq,
                                               const float* __restrict__ wk,
                                               const float* __restrict__ wv,
                                               const float* __restrict__ wo,
                                               u16* __restrict__ xb,
                                               u16* __restrict__ w3,
                                               u16* __restrict__ wob) {
    const int b = blockIdx.x;
    const float* s; u16* d; int off;
    const int NW = DMODEL * DMODEL;  // 1M
    if (b < 2048)      { s = x;  d = xb;          off = b * 2048; }
    else if (b < 2560) { s = wq; d = w3;          off = (b - 2048) * 2048; }
    else if (b < 3072) { s = wk; d = w3 + NW;     off = (b - 2560) * 2048; }
    else if (b < 3584) { s = wv; d = w3 + 2 * NW; off = (b - 3072) * 2048; }
    else               { s = wo; d = wob;         off = (b - 3584) * 2048; }
    const int i = off + threadIdx.x * 8;
    const float4 a = *(const float4*)(s + i);
    const float4 c = *(const float4*)(s + i + 4);
    u16 t[8];
    t[0] = f2bf(a.x); t[1] = f2bf(a.y); t[2] = f2bf(a.z); t[3] = f2bf(a.w);
    t[4] = f2bf(c.x); t[5] = f2bf(c.y); t[6] = f2bf(c.z); t[7] = f2bf(c.w);
    *(bf16x8*)(d + i) = *(const bf16x8*)t;
}

// Fused QKV projection: C = x(4096x1024) * W3^T (W3 = [wq;wk;wv] 3072x1024).
// Double-buffered single-barrier K-loop (BK=32). Q pre-scaled by 1/8*log2e.
// Q,K -> [h][m][c]; V -> [h][c][m].
__global__ __launch_bounds__(256) void gemm_qkv(const u16* __restrict__ A,
                                                const u16* __restrict__ B3,
                                                u16* __restrict__ Qo,
                                                u16* __restrict__ Ko,
                                                u16* __restrict__ Vo) {
    __shared__ __align__(16) u16 As[2][128 * 32];
    __shared__ __align__(16) u16 Bs[2][128 * 32];
    const int tid = threadIdx.x, lane = tid & 63, wave = tid >> 6;
    const int wm = (wave >> 1) * 64, wn = (wave & 1) * 64;
    const int m0 = blockIdx.y * 128, n0 = blockIdx.x * 128;
    const int l15 = lane & 15, quad = lane >> 4;

    f32x4 acc[4][4];
#pragma unroll
    for (int i = 0; i < 4; i++)
#pragma unroll
        for (int j = 0; j < 4; j++) acc[i][j] = (f32x4){0.f, 0.f, 0.f, 0.f};

    const int r0 = tid >> 2, c0 = (tid & 3) * 8;

    // prologue: stage k=0 into buf 0
    cp16(A + (size_t)(m0 + r0) * 1024 + c0,       As[0] + r0 * 32 + c0);
    cp16(A + (size_t)(m0 + r0 + 64) * 1024 + c0,  As[0] + (r0 + 64) * 32 + c0);
    cp16(B3 + (size_t)(n0 + r0) * 1024 + c0,      Bs[0] + r0 * 32 + c0);
    cp16(B3 + (size_t)(n0 + r0 + 64) * 1024 + c0, Bs[0] + (r0 + 64) * 32 + c0);

    int cur = 0;
    for (int kk = 0; kk < 1024; kk += 32) {
        __syncthreads();  // drains vmcnt(0): buf[cur] ready, buf[cur^1] reads done
        if (kk + 32 < 1024) {
            const int kn = kk + 32;
            cp16(A + (size_t)(m0 + r0) * 1024 + kn + c0,       As[cur ^ 1] + r0 * 32 + c0);
            cp16(A + (size_t)(m0 + r0 + 64) * 1024 + kn + c0,  As[cur ^ 1] + (r0 + 64) * 32 + c0);
            cp16(B3 + (size_t)(n0 + r0) * 1024 + kn + c0,      Bs[cur ^ 1] + r0 * 32 + c0);
            cp16(B3 + (size_t)(n0 + r0 + 64) * 1024 + kn + c0, Bs[cur ^ 1] + (r0 + 64) * 32 + c0);
        }
        bf16x8 af[4], bfr[4];
#pragma unroll
        for (int i = 0; i < 4; i++)
            af[i] = *(const bf16x8*)(As[cur] + (wm + i * 16 + l15) * 32 + quad * 8);
#pragma unroll
        for (int j = 0; j < 4; j++)
            bfr[j] = *(const bf16x8*)(Bs[cur] + (wn + j * 16 + l15) * 32 + quad * 8);
#pragma unroll
        for (int i = 0; i < 4; i++)
#pragma unroll
            for (int j = 0; j < 4; j++)
                acc[i][j] = __builtin_amdgcn_mfma_f32_16x16x32_bf16(af[i], bfr[j], acc[i][j], 0, 0, 0);
        cur ^= 1;
    }

    const int which = n0 >> 10;
    const int n0r = n0 & 1023;
    u16* dst = (which == 0) ? Qo : (which == 1) ? Ko : Vo;
    const float sc = (which == 0) ? 0.125f * 1.4426950408889634f : 1.0f;
#pragma unroll
    for (int i = 0; i < 4; i++)
#pragma unroll
        for (int j = 0; j < 4; j++)
#pragma unroll
            for (int r = 0; r < 4; r++) {
                const int row = m0 + wm + i * 16 + quad * 4 + r;
                const int col = n0r + wn + j * 16 + l15;
                const int h = col >> 6, c = col & 63;
                const u16 v = f2bf(acc[i][j][r] * sc);
                if (which < 2) dst[(size_t)h * S_LEN * 64 + (size_t)row * 64 + c] = v;
                else           dst[(size_t)h * S_LEN * 64 + (size_t)c * S_LEN + row] = v;
            }
}

// Output projection: C(fp32 [4096][1024]) = y(bf16) * wo^T. Split-M:
// 64x128 tiles, grid 512 (2/CU), BK=64, dbuf single-barrier, swizzled LDS,
// plain coalesced fp32 stores (no atomics, no memset).
__global__ __launch_bounds__(256) void gemm_out(const u16* __restrict__ A,
                                                const u16* __restrict__ B,
                                                float* __restrict__ C) {
    __shared__ __align__(16) u16 As[2][64 * 64];    // swizzled [row][col]
    __shared__ __align__(16) u16 Bs[2][128 * 64];   // swizzled [row][col]
    const int tid = threadIdx.x, lane = tid & 63, wave = tid >> 6;
    const int wm = (wave >> 1) * 32, wn = (wave & 1) * 64;
    const int bx = blockIdx.x;
    const int n0 = (bx & 7) * 128, m0 = (bx >> 3) * 64;
    const int l15 = lane & 15, quad = lane >> 4;
    const int swz = l15 & 7;

    f32x4 acc[2][4];
#pragma unroll
    for (int i = 0; i < 2; i++)
#pragma unroll
        for (int j = 0; j < 4; j++) acc[i][j] = (f32x4){0.f, 0.f, 0.f, 0.f};

#define STAGE_OUT(buf, kb)                                                              \
    {                                                                                   \
        _Pragma("unroll")                                                               \
        for (int q = 0; q < 2; q++) {                                                   \
            const int ch = tid + q * 256;                                               \
            const int ar = ch >> 3, ac = ((ch & 7) ^ (ar & 7)) * 8;                     \
            cp16(A + (size_t)(m0 + ar) * 1024 + (kb) + ac, As[buf] + ch * 8);           \
        }                                                                               \
        _Pragma("unroll")                                                               \
        for (int q = 0; q < 4; q++) {                                                   \
            const int ch = tid + q * 256;                                               \
            const int br = ch >> 3, bc = ((ch & 7) ^ (br & 7)) * 8;                     \
            cp16(B + (size_t)(n0 + br) * 1024 + (kb) + bc, Bs[buf] + ch * 8);           \
        }                                                                               \
    }

    STAGE_OUT(0, 0);
    int cur = 0;
    for (int kk = 0; kk < 1024; kk += 64) {
        __syncthreads();  // drains vmcnt(0): buf[cur] ready, buf[cur^1] reads done
        if (kk + 64 < 1024) STAGE_OUT(cur ^ 1, kk + 64);
#pragma unroll
        for (int h = 0; h < 2; h++) {
            const int cc = (h * 4 + quad) ^ swz;
            bf16x8 af[2], bfr[4];
#pragma unroll
            for (int i = 0; i < 2; i++)
                af[i] = *(const bf16x8*)(As[cur] + (wm + i * 16 + l15) * 64 + cc * 8);
#pragma unroll
            for (int j = 0; j < 4; j++)
                bfr[j] = *(const bf16x8*)(Bs[cur] + (wn + j * 16 + l15) * 64 + cc * 8);
#pragma unroll
            for (int i = 0; i < 2; i++)
#pragma unroll
                for (int j = 0; j < 4; j++)
                    acc[i][j] = __builtin_amdgcn_mfma_f32_16x16x32_bf16(af[i], bfr[j], acc[i][j], 0, 0, 0);
        }
        cur ^= 1;
    }
#undef STAGE_OUT

#pragma unroll
    for (int i = 0; i < 2; i++)
#pragma unroll
        for (int j = 0; j < 4; j++)
#pragma unroll
            for (int r = 0; r < 4; r++) {
                const int row = m0 + wm + i * 16 + quad * 4 + r;
                const int col = n0 + wn + j * 16 + l15;
                C[(size_t)row * 1024 + col] = acc[i][j][r];
            }
}

// Flash attention, causal (round-9 structure). Block = 4 waves; each wave
// owns 16 q-rows of SHORT tile A (rows 64j..) and 16 q-rows of LONG tile B
// (rows 64(63-j)..), fused in ONE K-loop; A participates while kt <= j.
// Every block does exactly 65 key-tile items -> balanced co-residency.
// Hot-loop VALU trimmed: bare v_exp_f32 + 3-op bf16 pack.
// Q (pre-scaled), K: [H][S][64] bf16. Vt: [H][64][S] bf16. Y: [S][DMODEL] bf16.
__global__ __launch_bounds__(256) void attn(const u16* __restrict__ Q,
                                            const u16* __restrict__ Kh,
                                            const u16* __restrict__ Vt,
                                            u16* __restrict__ Y) {
    __shared__ __align__(16) u16 Ks[2][64 * 64];   // swizzled [key][dim]
    __shared__ __align__(16) u16 Vs[2][64 * 64];   // swizzled [dim][key]
    __shared__ __align__(16) u16 Pl[4][32 * 72];   // [g*16+q][key], stride 72
    const int b = blockIdx.x;
    const int head = b & 15;
    const int bb = b >> 4;
    const int j = (b < 256) ? bb : 47 - bb;        // 0..15 then 31..16
    const int qaA = 64 * j;                        // short tile
    const int qaB = 64 * (63 - j);                 // long tile
    const int nktB = 64 - j;
    const int tid = threadIdx.x, lane = tid & 63, w = tid >> 6;
    const int l15 = lane & 15, quad = lane >> 4;
    const int swz = l15 & 7;

    const u16* Qp = Q + (size_t)head * S_LEN * 64;
    const u16* Kp = Kh + (size_t)head * S_LEN * 64;
    const u16* Vp = Vt + (size_t)head * 64 * S_LEN;

    const int qrowA = qaA + w * 16 + l15;
    const int qrowB = qaB + w * 16 + l15;
    const int srow = tid >> 3;
    const int scol = ((tid & 7) ^ (srow & 7)) * 8;

    bf16x8 aq[2][2];
#pragma unroll
    for (int s = 0; s < 2; s++) {
        aq[0][s] = *(const bf16x8*)(Qp + (size_t)qrowA * 64 + s * 32 + quad * 8);
        aq[1][s] = *(const bf16x8*)(Qp + (size_t)qrowB * 64 + s * 32 + quad * 8);
    }

    f32x4 o[2][4];
#pragma unroll
    for (int g = 0; g < 2; g++)
#pragma unroll
        for (int jj = 0; jj < 4; jj++) o[g][jj] = (f32x4){0.f, 0.f, 0.f, 0.f};
    float lrow[2] = {0.f, 0.f};

    // prologue: stage tile 0 into buf 0
    cp16(Kp + (size_t)srow * 64 + scol,        Ks[0] + tid * 8);
    cp16(Kp + (size_t)(srow + 32) * 64 + scol, Ks[0] + tid * 8 + 2048);
    cp16(Vp + (size_t)srow * S_LEN + scol,        Vs[0] + tid * 8);
    cp16(Vp + (size_t)(srow + 32) * S_LEN + scol, Vs[0] + tid * 8 + 2048);

    int cur = 0;
    for (int kt = 0; kt < nktB; kt++) {
        __syncthreads();  // drains vmcnt(0): buf[cur] ready, buf[cur^1] reads done
        if (kt + 1 < nktB) {
            const int kn = (kt + 1) * 64;
            cp16(Kp + (size_t)(kn + srow) * 64 + scol,      Ks[cur ^ 1] + tid * 8);
            cp16(Kp + (size_t)(kn + srow + 32) * 64 + scol, Ks[cur ^ 1] + tid * 8 + 2048);
            cp16(Vp + (size_t)srow * S_LEN + kn + scol,        Vs[cur ^ 1] + tid * 8);
            cp16(Vp + (size_t)(srow + 32) * S_LEN + kn + scol, Vs[cur ^ 1] + tid * 8 + 2048);
        }
        const u16* K_ = Ks[cur];
        const u16* V_ = Vs[cur];
        const int kb = kt * 64;
        const bool actA = (kt <= j);
        const bool bndA = (kt == j);
        const bool bndB = (kt == nktB - 1);
#pragma unroll
        for (int t = 0; t < 4; t++) {
            // K fragments read ONCE, shared by both groups
            const bf16x8 k0 = *(const bf16x8*)(K_ + (t * 16 + l15) * 64 + (quad ^ swz) * 8);
            const bf16x8 k1 = *(const bf16x8*)(K_ + (t * 16 + l15) * 64 + ((4 + quad) ^ swz) * 8);
            const int keyb = kb + t * 16 + quad * 4;
            // group B (long tile) always active
            {
                f32x4 c = (f32x4){0.f, 0.f, 0.f, 0.f};
                c = __builtin_amdgcn_mfma_f32_16x16x32_bf16(k0, aq[1][0], c, 0, 0, 0);
                c = __builtin_amdgcn_mfma_f32_16x16x32_bf16(k1, aq[1][1], c, 0, 0, 0);
                float p[4];
#pragma unroll
                for (int r = 0; r < 4; r++) {
                    p[r] = __builtin_amdgcn_exp2f(c[r]);
                    if (bndB && (keyb + r > qrowB)) p[r] = 0.f;
                }
                lrow[1] += (p[0] + p[1]) + (p[2] + p[3]);
                const u32 w0 = pkbf2f(p[0], p[1]);
                const u32 w1 = pkbf2f(p[2], p[3]);
                *(u64*)(&Pl[w][(16 + l15) * 72 + t * 16 + quad * 4]) =
                    (u64)w0 | ((u64)w1 << 32);
            }
            if (actA) {
                f32x4 c = (f32x4){0.f, 0.f, 0.f, 0.f};
                c = __builtin_amdgcn_mfma_f32_16x16x32_bf16(k0, aq[0][0], c, 0, 0, 0);
                c = __builtin_amdgcn_mfma_f32_16x16x32_bf16(k1, aq[0][1], c, 0, 0, 0);
                float p[4];
#pragma unroll
                for (int r = 0; r < 4; r++) {
                    p[r] = __builtin_amdgcn_exp2f(c[r]);
                    if (bndA && (keyb + r > qrowA)) p[r] = 0.f;
                }
                lrow[0] += (p[0] + p[1]) + (p[2] + p[3]);
                const u32 w0 = pkbf2f(p[0], p[1]);
                const u32 w1 = pkbf2f(p[2], p[3]);
                *(u64*)(&Pl[w][l15 * 72 + t * 16 + quad * 4]) =
                    (u64)w0 | ((u64)w1 << 32);
            }
        }
        bf16x8 pB0, pB1, pA0, pA1;
        pB0 = *(const bf16x8*)(&Pl[w][(16 + l15) * 72 + quad * 8]);
        pB1 = *(const bf16x8*)(&Pl[w][(16 + l15) * 72 + 32 + quad * 8]);
        if (actA) {
            pA0 = *(const bf16x8*)(&Pl[w][l15 * 72 + quad * 8]);
            pA1 = *(const bf16x8*)(&Pl[w][l15 * 72 + 32 + quad * 8]);
        }
#pragma unroll
        for (int jj = 0; jj < 4; jj++) {
            // V fragments read ONCE, shared by both groups
            const bf16x8 v0 = *(const bf16x8*)(V_ + (jj * 16 + l15) * 64 + (quad ^ swz) * 8);
            const bf16x8 v1 = *(const bf16x8*)(V_ + (jj * 16 + l15) * 64 + ((4 + quad) ^ swz) * 8);
            o[1][jj] = __builtin_amdgcn_mfma_f32_16x16x32_bf16(v0, pB0, o[1][jj], 0, 0, 0);
            o[1][jj] = __builtin_amdgcn_mfma_f32_16x16x32_bf16(v1, pB1, o[1][jj], 0, 0, 0);
            if (actA) {
                o[0][jj] = __builtin_amdgcn_mfma_f32_16x16x32_bf16(v0, pA0, o[0][jj], 0, 0, 0);
                o[0][jj] = __builtin_amdgcn_mfma_f32_16x16x32_bf16(v1, pA1, o[0][jj], 0, 0, 0);
            }
        }
        cur ^= 1;
    }

#pragma unroll
    for (int g = 0; g < 2; g++) {
        lrow[g] += __shfl_xor(lrow[g], 16);
        lrow[g] += __shfl_xor(lrow[g], 32);
        const float inv = 1.f / lrow[g];
        const int qrow = (g == 0) ? qrowA : qrowB;
#pragma unroll
        for (int jj = 0; jj < 4; jj++) {
            const u32 w0 = pkbf2(o[g][jj][0] * inv, o[g][jj][1] * inv);
            const u32 w1 = pkbf2(o[g][jj][2] * inv, o[g][jj][3] * inv);
            *(u64*)(Y + (size_t)qrow * DMODEL + head * 64 + jj * 16 + quad * 4) =
                (u64)w0 | ((u64)w1 << 32);
        }
    }
}

extern "C" void kernel_launch(void* const* d_in, const int* in_sizes, int n_in,
                              void* d_out, int out_size, void* d_ws, size_t ws_size,
                              hipStream_t stream) {
    const float* x  = (const float*)d_in[0];
    const float* wq = (const float*)d_in[1];
    const float* wk = (const float*)d_in[2];
    const float* wv = (const float*)d_in[3];
    const float* wo = (const float*)d_in[4];
    float* out = (float*)d_out;

    u16* qh  = (u16*)d_ws;                            // [0,8) MB
    u16* kh  = qh + (size_t)S_LEN * DMODEL;           // [8,16)
    u16* vt  = kh + (size_t)S_LEN * DMODEL;           // [16,24)
    u16* xb  = vt + (size_t)S_LEN * DMODEL;           // [24,32) x bf16, later y
    u16* y   = xb;                                    // alias after QKV proj
    u16* wb3 = xb + (size_t)S_LEN * DMODEL;           // [32,38) [wq;wk;wv]
    u16* wob = wb3 + (size_t)3 * DMODEL * DMODEL;     // [38,40) wo bf16

    const dim3 blk(256);

    cvt_all<<<4096, blk, 0, stream>>>(x, wq, wk, wv, wo, xb, wb3, wob);
    gemm_qkv<<<dim3(3 * DMODEL / 128, S_LEN / 128), blk, 0, stream>>>(xb, wb3, qh, kh, vt);
    attn<<<512, blk, 0, stream>>>(qh, kh, vt, y);
    gemm_out<<<512, blk, 0, stream>>>(y, wob, out);
}